// Round 4
// baseline (217.508 us; speedup 1.0000x reference)
//
#include <hip/hip_runtime.h>

// y = W @ x + bias, W in COO (rows sorted), fp32.
// R9: R5 base (nt streams, plain fallbacks — best measured 77.9us) with ONE
// change: x-gathers go through the LDS-DMA path (global_load_lds, size=4,
// per-lane global address, wave-uniform LDS base + lane*4). Motivation:
// four structurally different kernels all land 77-91us; implied outstanding
// gather-lines/CU (~54 avg) sits at the TCP miss-tracking cap, so the only
// remaining lever is a memory path with separate/deeper request tracking.
// If this is neutral, the per-CU miss-concurrency roofline is confirmed.

constexpr int       CHUNK = 8;                        // nnz per thread
constexpr int       BLOCK = 256;
constexpr long long SPAN  = (long long)BLOCK * CHUNK; // 2048 nnz per block
constexpr int       RMAX  = 768;                      // LDS acc slots (3 KB)
constexpr int       WAVES = BLOCK / 64;
constexpr int       GSLOT = CHUNK * 64;               // floats per wave region

typedef float vfloat4 __attribute__((ext_vector_type(4)));
typedef int   vint4   __attribute__((ext_vector_type(4)));
typedef const __attribute__((address_space(1))) void gas_void;
typedef __attribute__((address_space(3))) void las_void;

__global__ void init_y_bias(const float* __restrict__ bias,
                            float* __restrict__ y, int n) {
    int i = blockIdx.x * blockDim.x + threadIdx.x;
    if (i < n) y[i] = bias[i];
}

__device__ __forceinline__ void lds_add(float* p, float v) {
    // workgroup-scope relaxed fp add -> ds_add_f32 (no TCC involvement)
    __hip_atomic_fetch_add(p, v, __ATOMIC_RELAXED, __HIP_MEMORY_SCOPE_WORKGROUP);
}

// Barrier waiting ONLY on LDS/SMEM (lgkmcnt): acc-zero stores and ds_adds
// are lgkm-tracked; streaming loads and LDS-DMA gathers (vmcnt) stay in
// flight across it.
__device__ __forceinline__ void barrier_lds_only() {
    asm volatile("s_waitcnt lgkmcnt(0)" ::: "memory");
    __builtin_amdgcn_s_barrier();
}

__global__ __launch_bounds__(BLOCK) void spmv_coo_lds(
        const float* __restrict__ vals,
        const float* __restrict__ x,
        const int*   __restrict__ rows,
        const int*   __restrict__ cols,
        const float* __restrict__ bias,
        float*       __restrict__ y,
        long long nnz) {
    __shared__ float acc[RMAX];
    __shared__ float gbuf[WAVES * GSLOT];             // 8 KB: per-wave gather dest
    const int tid  = threadIdx.x;
    const int wid  = tid >> 6;
    const int lane = tid & 63;
    const long long b0 = (long long)blockIdx.x * SPAN;
    if (b0 >= nnz) return;                       // whole block exits uniformly
    const long long bend = (b0 + SPAN < nnz) ? (b0 + SPAN) : nnz;
    const bool full = (b0 + SPAN) <= nnz;        // block-uniform

    // ---- issue streaming loads FIRST: cols first (gather DMAs depend on
    //      them; vmcnt wait before DMA issue then leaves v/r in flight) ----
    float v[CHUNK]; int r[CHUNK]; int c[CHUNK];
    const long long i0 = b0 + (long long)tid * CHUNK;
    if (full) {
        const vint4*   c4 = reinterpret_cast<const vint4*>(cols + i0);
        const vfloat4* v4 = reinterpret_cast<const vfloat4*>(vals + i0);
        const vint4*   r4 = reinterpret_cast<const vint4*>(rows + i0);
        #pragma unroll
        for (int q = 0; q < CHUNK / 4; ++q) {
            vint4 cc = __builtin_nontemporal_load(c4 + q);
            #pragma unroll
            for (int j = 0; j < 4; ++j) c[4*q+j] = cc[j];
        }
        #pragma unroll
        for (int q = 0; q < CHUNK / 4; ++q) {
            vfloat4 vv = __builtin_nontemporal_load(v4 + q);
            vint4   rr = __builtin_nontemporal_load(r4 + q);
            #pragma unroll
            for (int j = 0; j < 4; ++j) { v[4*q+j] = vv[j]; r[4*q+j] = rr[j]; }
        }
    }

    // ---- prologue: zero acc (overlaps cols latency) ----
    #pragma unroll
    for (int i = tid; i < RMAX; i += BLOCK) acc[i] = 0.f;
    const int r0    = rows[b0];
    const int rl    = rows[bend - 1];
    const int range = rl - r0 + 1;

    // ---- issue the 8 LDS-DMA gathers: per-lane global addr, per-wave LDS
    //      region; lands at gbuf[wid*GSLOT + k*64 + lane] ----
    if (full) {
        float* gw = &gbuf[wid * GSLOT];
        #pragma unroll
        for (int k = 0; k < CHUNK; ++k) {
            __builtin_amdgcn_global_load_lds(
                (gas_void*)(x + c[k]),
                (las_void*)(gw + k * 64),
                4, 0, 0);
        }
    }

    // acc zeros visible; streams + gather DMAs stay in flight
    barrier_lds_only();

    if (range <= RMAX) {
        if (full) {
            // drain this wave's vmem (gather DMAs + v/r streams), then read
            // gathered x back from LDS (stride-1 per lane: conflict-free)
            asm volatile("s_waitcnt vmcnt(0)" ::: "memory");
            __builtin_amdgcn_sched_barrier(0);
            const float* gw = &gbuf[wid * GSLOT];
            float g[CHUNK];
            #pragma unroll
            for (int k = 0; k < CHUNK; ++k) g[k] = gw[k * 64 + lane];

            int   cur = r[0];
            float sum = v[0] * g[0];
            #pragma unroll
            for (int k = 1; k < CHUNK; ++k) {
                if (r[k] != cur) {               // row boundary: flush run
                    lds_add(&acc[cur - r0], sum);
                    cur = r[k];
                    sum = 0.f;
                }
                sum += v[k] * g[k];
            }
            lds_add(&acc[cur - r0], sum);
        } else if (i0 < bend) {
            // scalar partial-block path (cold: only the last block)
            int   cur = rows[i0];
            float sum = 0.f;
            long long kend = (i0 + CHUNK < bend) ? (i0 + CHUNK) : bend;
            for (long long k = i0; k < kend; ++k) {
                int rk = rows[k];
                if (rk != cur) { lds_add(&acc[cur - r0], sum); sum = 0.f; cur = rk; }
                sum += vals[k] * x[cols[k]];
            }
            lds_add(&acc[cur - r0], sum);
        }
        barrier_lds_only();                      // ds_adds complete

        // ---- coalesced epilogue: interior rows exclusively owned ----
        for (int i = tid; i < range; i += BLOCK) {
            int   rr = r0 + i;
            float a  = acc[i];
            if (rr == r0 || rr == rl) {
                if (a != 0.f) atomicAdd(&y[rr], a);  // may span block boundary
            } else {
                y[rr] = bias[rr] + a;                // plain coalesced store
            }
        }
    } else {
        // pathological row-gap fallback (never hit on this data): plain
        // gathers + per-thread global atomics
        asm volatile("s_waitcnt vmcnt(0)" ::: "memory");  // retire DMAs
        if (i0 < bend) {
            if (full) {
                float g[CHUNK];
                #pragma unroll
                for (int k = 0; k < CHUNK; ++k) g[k] = x[c[k]];
                int   cur = r[0];
                float sum = v[0] * g[0];
                #pragma unroll
                for (int k = 1; k < CHUNK; ++k) {
                    if (r[k] != cur) { atomicAdd(&y[cur], sum); sum = 0.f; cur = r[k]; }
                    sum += v[k] * g[k];
                }
                atomicAdd(&y[cur], sum);
            } else {
                int   cur = rows[i0];
                float sum = 0.f;
                long long kend = (i0 + CHUNK < bend) ? (i0 + CHUNK) : bend;
                for (long long k = i0; k < kend; ++k) {
                    int rk = rows[k];
                    if (rk != cur) { atomicAdd(&y[cur], sum); sum = 0.f; cur = rk; }
                    sum += vals[k] * x[cols[k]];
                }
                atomicAdd(&y[cur], sum);
            }
        }
    }
}

extern "C" void kernel_launch(void* const* d_in, const int* in_sizes, int n_in,
                              void* d_out, int out_size, void* d_ws, size_t ws_size,
                              hipStream_t stream) {
    const float* vals = (const float*)d_in[0];
    const float* x    = (const float*)d_in[1];
    const float* bias = (const float*)d_in[2];
    const int*   rows = (const int*)d_in[3];
    const int*   cols = (const int*)d_in[4];
    float* y = (float*)d_out;

    const long long nnz = in_sizes[0];
    const int n_rows    = in_sizes[2];   // len(bias) == n_rows

    // 1) y = bias (covers empty gap-rows + rows receiving boundary atomics)
    {
        int threads = 256;
        int blocks  = (n_rows + threads - 1) / threads;
        init_y_bias<<<blocks, threads, 0, stream>>>(bias, y, n_rows);
    }

    // 2) block-local LDS-accumulated COO reduce, LDS-DMA gather path
    {
        long long blocks = (nnz + SPAN - 1) / SPAN;
        spmv_coo_lds<<<(int)blocks, BLOCK, 0, stream>>>(
            vals, x, rows, cols, bias, y, nnz);
    }
}